// Round 2
// baseline (3632.976 us; speedup 1.0000x reference)
//
#include <hip/hip_runtime.h>
#include <hip/hip_bf16.h>
#include <math.h>

#define BSZ   128
#define NENT  512
#define NP1   513
#define DENT  256
#define KDIM  128
#define DIN   1024
#define DF    256
#define HDIM  128
#define SSTEP 64
#define G4    512
#define NEGV  (-1e9f)
#define INV_MAX (1.0f/512.0f)

// ---------------- helpers ----------------
__device__ inline float sigf(float x){ return 1.f/(1.f+__expf(-x)); }
__device__ inline float bf_lo(unsigned u){ return __uint_as_float(u<<16); }
__device__ inline float bf_hi(unsigned u){ return __uint_as_float(u & 0xffff0000u); }

// block = 512 threads (8 waves). Returns sums over the block to ALL threads.
__device__ inline float2 block_reduce2(float x, float y, float* red){
  #pragma unroll
  for(int o=32;o>0;o>>=1){ x += __shfl_down(x,o,64); y += __shfl_down(y,o,64); }
  int w = threadIdx.x>>6;
  __syncthreads();
  if((threadIdx.x&63)==0){ red[w]=x; red[8+w]=y; }
  __syncthreads();
  float sx=0.f, sy=0.f;
  #pragma unroll
  for(int q=0;q<8;q++){ sx+=red[q]; sy+=red[8+q]; }
  return make_float2(sx,sy);
}

__device__ inline void block_reduce4(float a,float b,float c,float d, float* red, float out[4]){
  #pragma unroll
  for(int o=32;o>0;o>>=1){
    a += __shfl_down(a,o,64); b += __shfl_down(b,o,64);
    c += __shfl_down(c,o,64); d += __shfl_down(d,o,64);
  }
  int w = threadIdx.x>>6;
  __syncthreads();
  if((threadIdx.x&63)==0){ red[w]=a; red[8+w]=b; red[16+w]=c; red[24+w]=d; }
  __syncthreads();
  float s0=0.f,s1=0.f,s2=0.f,s3=0.f;
  #pragma unroll
  for(int q=0;q<8;q++){ s0+=red[q]; s1+=red[8+q]; s2+=red[16+q]; s3+=red[24+q]; }
  out[0]=s0; out[1]=s1; out[2]=s2; out[3]=s3;
}

// ---------------- generic tiled GEMM: C[M,N] = act(A[M,K] @ B^T + bias) ----------------
template<bool BKMAJOR, bool RELU, bool KEYMAP>
__global__ __launch_bounds__(256)
void gemm_kernel(const float* __restrict__ A, const float* __restrict__ B,
                 const float* __restrict__ bias, float* __restrict__ C,
                 int M, int N, int K){
  __shared__ float As[16][64];
  __shared__ float Bs[16][64];
  const int bm = blockIdx.x, bn = blockIdx.y;
  const int t = threadIdx.x;
  const int tm = t>>4, tn = t&15;
  float acc[16];
  #pragma unroll
  for(int q=0;q<16;q++) acc[q]=0.f;

  const int ml = t>>2;          // 0..63
  const int kq = (t&3)*4;       // 0,4,8,12

  for(int k0=0;k0<K;k0+=16){
    {
      float4 av = *(const float4*)&A[(size_t)(bm*64+ml)*K + k0 + kq];
      As[kq+0][ml]=av.x; As[kq+1][ml]=av.y; As[kq+2][ml]=av.z; As[kq+3][ml]=av.w;
    }
    if(!BKMAJOR){
      float4 bv = *(const float4*)&B[(size_t)(bn*64+ml)*K + k0 + kq];
      Bs[kq+0][ml]=bv.x; Bs[kq+1][ml]=bv.y; Bs[kq+2][ml]=bv.z; Bs[kq+3][ml]=bv.w;
    } else {
      int kl = t>>4;
      int nq = (t&15)*4;
      float4 bv = *(const float4*)&B[(size_t)(k0+kl)*N + bn*64 + nq];
      *(float4*)&Bs[kl][nq] = bv;
    }
    __syncthreads();
    #pragma unroll
    for(int k=0;k<16;k++){
      float4 a4 = *(const float4*)&As[k][tm<<2];
      float4 b4 = *(const float4*)&Bs[k][tn<<2];
      float av[4] = {a4.x,a4.y,a4.z,a4.w};
      float bv[4] = {b4.x,b4.y,b4.z,b4.w};
      #pragma unroll
      for(int mi=0;mi<4;mi++)
        #pragma unroll
        for(int ni=0;ni<4;ni++)
          acc[mi*4+ni] = fmaf(av[mi], bv[ni], acc[mi*4+ni]);
    }
    __syncthreads();
  }
  #pragma unroll
  for(int mi=0;mi<4;mi++){
    int gm = (bm<<6)+(tm<<2)+mi;
    size_t orow = KEYMAP ? ((size_t)(gm>>9)*NP1 + (gm&511)) : (size_t)gm;
    #pragma unroll
    for(int ni=0;ni<4;ni++){
      int gn = (bn<<6)+(tn<<2)+ni;
      float v = acc[mi*4+ni];
      if(bias) v += bias[gn];
      if(RELU) v = fmaxf(v,0.f);
      C[orow*N + gn] = v;
    }
  }
}

// ---------------- key fixups: end-embedding row + zero row 512 ----------------
__global__ void fixup_end(const int* __restrict__ en, const float* __restrict__ end_emb,
                          float* __restrict__ key){
  int b = blockIdx.x, k = threadIdx.x;  // 128 x 128
  int e = en[b];
  key[((size_t)b*NP1 + NENT)*KDIM + k] = 0.f;
  key[((size_t)b*NP1 + e)*KDIM + k] = end_emb[k];
}

// ---------------- gather selected key rows, scaled ----------------
__global__ void gather_kr(const int* __restrict__ su, const float* __restrict__ key,
                          float* __restrict__ KR){
  int idx = blockIdx.x*256 + threadIdx.x;  // 8192*128
  int r = idx >> 7, k = idx & 127;
  int b = r >> 6;
  int s = su[r];
  KR[idx] = key[((size_t)b*NP1 + s)*KDIM + k] * INV_MAX;
}

// ---------------- c0v[f] = q1_w[f,:] . e2_b ----------------
__global__ void c0_kernel(const float* __restrict__ q1_w, const float* __restrict__ e2_b,
                          float* __restrict__ c0v){
  int f = threadIdx.x; // 1 block x 256
  float acc=0.f;
  for(int d=0;d<DIN;d++) acc = fmaf(q1_w[(size_t)f*DIN+d], e2_b[d], acc);
  c0v[f]=acc;
}

// ---------------- gated exclusive prefix over steps; emits relu(U), s1, ng ----------------
__global__ void prefix_kernel(const float* __restrict__ U0, const float* __restrict__ Q1K,
                              const float* __restrict__ c0v, const float* __restrict__ T1,
                              const int* __restrict__ su, const int* __restrict__ en,
                              const int* __restrict__ sun,
                              float* __restrict__ RU, float* __restrict__ s1,
                              float* __restrict__ ngout){
  int b = blockIdx.x, f = threadIdx.x;    // 128 x 256
  float acc = U0[b*DF+f];
  float c0f = c0v[f];
  float s1a = 0.f, ng = 0.f;
  int enb = en[b], sunb = sun[b];
  for(int j=0;j<SSTEP;j++){
    int r = b*SSTEP+j;
    float q = Q1K[(size_t)r*DF+f];
    float tt = T1[(size_t)r*DF+f];
    RU[(size_t)r*DF+f] = fmaxf(acc,0.f);
    int sj = su[r];
    float g = ((j+1)<=sunb && sj!=enb) ? 1.f : 0.f;
    acc = fmaf(g, q + c0f, acc);
    s1a = fmaf(g, tt, s1a);
    ng += g;
  }
  s1[b*DF+f]=s1a;
  if(f==0) ngout[b]=ng;
}

// ---------------- in-place LayerNorm over rows of 512 ----------------
__global__ __launch_bounds__(512)
void ln512(float* __restrict__ G, const float* __restrict__ gam, const float* __restrict__ bet){
  __shared__ float red[32];
  size_t r = blockIdx.x;
  int j = threadIdx.x;
  float v = G[r*G4+j];
  float2 s = block_reduce2(v, v*v, red);
  float mu = s.x*(1.f/512.f);
  float rs = rsqrtf(s.y*(1.f/512.f) - mu*mu + 1e-5f);
  G[r*G4+j] = (v-mu)*rs*gam[j] + bet[j];
}

// ---------------- serial 2-layer LN-LSTM scan (1 block per batch) ----------------
// Weights register-resident: thread j owns row j of whh0, wih1, whh1, packed bf16x2.
__global__ __launch_bounds__(512,2)
void lstm_serial(const float* __restrict__ wih, const float* __restrict__ whh,
                 const float* __restrict__ G0,
                 const float* __restrict__ ln_ig, const float* __restrict__ ln_ib,
                 const float* __restrict__ ln_hg, const float* __restrict__ ln_hb,
                 const float* __restrict__ ln_cg, const float* __restrict__ ln_cb,
                 float* __restrict__ H1){
  const int b = blockIdx.x;
  const int j = threadIdx.x;
  __shared__ float h0s[128], h1s[128], ash[512];
  __shared__ float red[32];

  // one-time: pack weight rows into registers (bf16 pairs, truncation)
  unsigned w0p[64], w1p[64], w2p[64];
  #pragma unroll
  for(int kb=0;kb<32;kb++){
    float4 a = *(const float4*)&whh[(size_t)j*KDIM + kb*4];
    w0p[2*kb]   = (__float_as_uint(a.y)&0xffff0000u) | (__float_as_uint(a.x)>>16);
    w0p[2*kb+1] = (__float_as_uint(a.w)&0xffff0000u) | (__float_as_uint(a.z)>>16);
  }
  #pragma unroll
  for(int kb=0;kb<32;kb++){
    float4 a = *(const float4*)&wih[65536 + (size_t)j*KDIM + kb*4];
    w1p[2*kb]   = (__float_as_uint(a.y)&0xffff0000u) | (__float_as_uint(a.x)>>16);
    w1p[2*kb+1] = (__float_as_uint(a.w)&0xffff0000u) | (__float_as_uint(a.z)>>16);
  }
  #pragma unroll
  for(int kb=0;kb<32;kb++){
    float4 a = *(const float4*)&whh[65536 + (size_t)j*KDIM + kb*4];
    w2p[2*kb]   = (__float_as_uint(a.y)&0xffff0000u) | (__float_as_uint(a.x)>>16);
    w2p[2*kb+1] = (__float_as_uint(a.w)&0xffff0000u) | (__float_as_uint(a.z)>>16);
  }

  const float hg0 = ln_hg[j],     hb0 = ln_hb[j];
  const float ig1 = ln_ig[512+j], ib1 = ln_ib[512+j];
  const float hg1 = ln_hg[512+j], hb1 = ln_hb[512+j];
  float cg0=0.f,cb0=0.f,cg1=0.f,cb1=0.f,c0r=0.f,c1r=0.f;
  if(j<128){ cg0=ln_cg[j]; cb0=ln_cb[j]; cg1=ln_cg[128+j]; cb1=ln_cb[128+j]; h0s[j]=0.f; h1s[j]=0.f; }
  __syncthreads();

  const float4* h04 = (const float4*)h0s;
  const float4* h14 = (const float4*)h1s;

  for(int i=0;i<SSTEP;i++){
    // prefetch this step's precomputed layer-0 input gates
    float g0v = G0[((size_t)b*SSTEP+i)*G4 + j];

    // layer 0: v = whh0 @ h0  (reg weights, LDS-broadcast h)
    float v = 0.f, vb = 0.f;
    #pragma unroll
    for(int kb=0;kb<32;kb+=2){
      float4 ha = h04[kb];
      v  = fmaf(bf_lo(w0p[2*kb  ]),ha.x,v ); v  = fmaf(bf_hi(w0p[2*kb  ]),ha.y,v );
      v  = fmaf(bf_lo(w0p[2*kb+1]),ha.z,v ); v  = fmaf(bf_hi(w0p[2*kb+1]),ha.w,v );
      float4 hb = h04[kb+1];
      vb = fmaf(bf_lo(w0p[2*kb+2]),hb.x,vb); vb = fmaf(bf_hi(w0p[2*kb+2]),hb.y,vb);
      vb = fmaf(bf_lo(w0p[2*kb+3]),hb.z,vb); vb = fmaf(bf_hi(w0p[2*kb+3]),hb.w,vb);
    }
    v += vb;
    float2 s = block_reduce2(v, v*v, red);
    float mu = s.x*(1.f/512.f);
    float rs = rsqrtf(s.y*(1.f/512.f) - mu*mu + 1e-5f);
    ash[j] = g0v + (v-mu)*rs*hg0 + hb0;
    __syncthreads();
    float cpre = 0.f;
    if(j<128){
      float gi=ash[j], gf=ash[j+128], gg=ash[j+256];
      cpre = sigf(gf)*c0r + sigf(gi)*tanhf(gg);
    }
    float2 sc = block_reduce2(j<128?cpre:0.f, j<128?cpre*cpre:0.f, red);
    float muc = sc.x*(1.f/128.f);
    float rsc = rsqrtf(sc.y*(1.f/128.f) - muc*muc + 1e-5f);
    if(j<128){
      c0r = (cpre-muc)*rsc*cg0 + cb0;
      h0s[j] = sigf(ash[j+384])*tanhf(c0r);
    }
    __syncthreads();

    // layer 1: u = wih1 @ h0,  v1 = whh1 @ h1
    float u=0.f, ub=0.f, v1=0.f, v1b=0.f;
    #pragma unroll
    for(int kb=0;kb<32;kb++){
      float4 ha = h04[kb];
      float4 hb = h14[kb];
      if(kb&1){
        ub  = fmaf(bf_lo(w1p[2*kb  ]),ha.x,ub ); ub  = fmaf(bf_hi(w1p[2*kb  ]),ha.y,ub );
        ub  = fmaf(bf_lo(w1p[2*kb+1]),ha.z,ub ); ub  = fmaf(bf_hi(w1p[2*kb+1]),ha.w,ub );
        v1b = fmaf(bf_lo(w2p[2*kb  ]),hb.x,v1b); v1b = fmaf(bf_hi(w2p[2*kb  ]),hb.y,v1b);
        v1b = fmaf(bf_lo(w2p[2*kb+1]),hb.z,v1b); v1b = fmaf(bf_hi(w2p[2*kb+1]),hb.w,v1b);
      } else {
        u  = fmaf(bf_lo(w1p[2*kb  ]),ha.x,u ); u  = fmaf(bf_hi(w1p[2*kb  ]),ha.y,u );
        u  = fmaf(bf_lo(w1p[2*kb+1]),ha.z,u ); u  = fmaf(bf_hi(w1p[2*kb+1]),ha.w,u );
        v1 = fmaf(bf_lo(w2p[2*kb  ]),hb.x,v1); v1 = fmaf(bf_hi(w2p[2*kb  ]),hb.y,v1);
        v1 = fmaf(bf_lo(w2p[2*kb+1]),hb.z,v1); v1 = fmaf(bf_hi(w2p[2*kb+1]),hb.w,v1);
      }
    }
    u += ub; v1 += v1b;
    float s4[4];
    block_reduce4(u,u*u,v1,v1*v1,red,s4);
    float muu = s4[0]*(1.f/512.f);
    float rsu = rsqrtf(s4[1]*(1.f/512.f) - muu*muu + 1e-5f);
    float muv = s4[2]*(1.f/512.f);
    float rsv = rsqrtf(s4[3]*(1.f/512.f) - muv*muv + 1e-5f);
    ash[j] = (u-muu)*rsu*ig1 + ib1 + (v1-muv)*rsv*hg1 + hb1;
    __syncthreads();
    float cpre1 = 0.f;
    if(j<128){
      float gi=ash[j], gf=ash[j+128], gg=ash[j+256];
      cpre1 = sigf(gf)*c1r + sigf(gi)*tanhf(gg);
    }
    float2 sc1 = block_reduce2(j<128?cpre1:0.f, j<128?cpre1*cpre1:0.f, red);
    float muc1 = sc1.x*(1.f/128.f);
    float rsc1 = rsqrtf(sc1.y*(1.f/128.f) - muc1*muc1 + 1e-5f);
    if(j<128){
      c1r = (cpre1-muc1)*rsc1*cg1 + cb1;
      float h1n = sigf(ash[j+384])*tanhf(c1r);
      h1s[j] = h1n;
      H1[((size_t)b*SSTEP+i)*HDIM + j] = h1n;
    }
    __syncthreads();
  }
}

// ---------------- logits: per-batch H1 @ key^T with mask ----------------
__global__ __launch_bounds__(256)
void logits_kernel(const float* __restrict__ key, const float* __restrict__ H1,
                   const int* __restrict__ en, const int* __restrict__ su,
                   float* __restrict__ out){
  const int b = blockIdx.x;
  __shared__ float HsT[128][68];       // [k][i], padded
  __shared__ int firstsel[NP1];
  for(int t=threadIdx.x; t<SSTEP*HDIM; t+=256){
    int i = t>>7, k = t&127;
    HsT[k][i] = H1[(size_t)b*SSTEP*HDIM + t];
  }
  for(int t=threadIdx.x; t<NP1; t+=256) firstsel[t] = 1<<30;
  __syncthreads();
  if(threadIdx.x < SSTEP) atomicMin(&firstsel[su[b*SSTEP+threadIdx.x]], (int)threadIdx.x);
  __syncthreads();
  const int enb = en[b];
  for(int n=threadIdx.x; n<NP1; n+=256){
    if(n > enb){
      for(int i=0;i<SSTEP;i++) out[((size_t)b*SSTEP+i)*NP1 + n] = NEGV;
      continue;
    }
    const float* kr = key + ((size_t)b*NP1 + n)*KDIM;
    const int fs = firstsel[n];
    for(int it=0; it<SSTEP; it+=16){
      float acc[16];
      #pragma unroll
      for(int q=0;q<16;q++) acc[q]=0.f;
      for(int k=0;k<KDIM;k+=4){
        float4 kv = *(const float4*)&kr[k];
        float kvs[4] = {kv.x,kv.y,kv.z,kv.w};
        #pragma unroll
        for(int kk=0;kk<4;kk++){
          #pragma unroll
          for(int qq=0;qq<4;qq++){
            float4 hv = *(const float4*)&HsT[k+kk][it+qq*4];
            acc[qq*4+0] = fmaf(kvs[kk], hv.x, acc[qq*4+0]);
            acc[qq*4+1] = fmaf(kvs[kk], hv.y, acc[qq*4+1]);
            acc[qq*4+2] = fmaf(kvs[kk], hv.z, acc[qq*4+2]);
            acc[qq*4+3] = fmaf(kvs[kk], hv.w, acc[qq*4+3]);
          }
        }
      }
      #pragma unroll
      for(int q=0;q<16;q++){
        int i = it+q;
        bool m = (fs >= i) && !(i==0 && n==enb);
        out[((size_t)b*SSTEP+i)*NP1 + n] = m ? acc[q] : NEGV;
      }
    }
  }
}

// ---------------- final ae + selected_units_num ----------------
__global__ void ae_out_kernel(const float* __restrict__ emb, const float* __restrict__ P,
                              const float* __restrict__ e2_b, const float* __restrict__ ng,
                              const int* __restrict__ sun, float* __restrict__ out){
  const size_t AE_OFF = (size_t)BSZ*SSTEP*NP1;
  const size_t SUN_OFF = AE_OFF + (size_t)BSZ*DIN;
  int idx = blockIdx.x*256+threadIdx.x;   // 131072
  int b = idx>>10, d = idx&1023;
  out[AE_OFF + idx] = emb[idx] + P[idx] + ng[b]*e2_b[d];
  if(idx < BSZ) out[SUN_OFF + idx] = (float)sun[idx];
}

// ---------------- launch ----------------
extern "C" void kernel_launch(void* const* d_in, const int* in_sizes, int n_in,
                              void* d_out, int out_size, void* d_ws, size_t ws_size,
                              hipStream_t stream){
  const float* emb     = (const float*)d_in[0];
  const float* ent     = (const float*)d_in[1];
  const float* key_w   = (const float*)d_in[2];
  const float* key_b   = (const float*)d_in[3];
  const float* q1_w    = (const float*)d_in[4];
  const float* q1_b    = (const float*)d_in[5];
  const float* q2_w    = (const float*)d_in[6];
  const float* q2_b    = (const float*)d_in[7];
  const float* e1_w    = (const float*)d_in[8];
  const float* e1_b    = (const float*)d_in[9];
  const float* e2_w    = (const float*)d_in[10];
  const float* e2_b    = (const float*)d_in[11];
  const float* end_emb = (const float*)d_in[12];
  const float* wih     = (const float*)d_in[13];
  const float* whh     = (const float*)d_in[14];
  const float* ln_ig   = (const float*)d_in[15];
  const float* ln_ib   = (const float*)d_in[16];
  const float* ln_hg   = (const float*)d_in[17];
  const float* ln_hb   = (const float*)d_in[18];
  const float* ln_cg   = (const float*)d_in[19];
  const float* ln_cb   = (const float*)d_in[20];
  const int* en  = (const int*)d_in[21];
  const int* su  = (const int*)d_in[22];
  const int* sun = (const int*)d_in[23];
  float* out = (float*)d_out;
  float* ws  = (float*)d_ws;

  // workspace layout (float units)
  const size_t o_key = 0;                       // 128*513*128 = 8,404,992
  const size_t o_KR  = o_key + 8404992;         // 1,048,576
  const size_t o_T1  = o_KR  + 1048576;         // 2,097,152
  const size_t o_q1e = o_T1  + 2097152;         // 65,536
  const size_t o_c0  = o_q1e + 65536;           // 1,024 (256 used)
  const size_t o_U0  = o_c0  + 1024;            // 32,768
  const size_t o_Q1K = o_U0  + 32768;           // 2,097,152
  const size_t o_RU  = o_Q1K + 2097152;         // 2,097,152
  const size_t o_X   = o_RU  + 2097152;         // 1,048,576
  const size_t o_G0  = o_X   + 1048576;         // 4,194,304
  const size_t o_s1  = o_G0  + 4194304;         // 32,768
  const size_t o_ng  = o_s1  + 32768;           // 1,024 (128 used)
  const size_t o_H1  = o_ng  + 1024;            // 1,048,576
  const size_t o_P   = o_H1  + 1048576;         // 131,072

  // 1) key = ent_emb @ key_w^T + key_b  (rows mapped into 513-stride layout)
  gemm_kernel<false,false,true><<<dim3(1024,2),256,0,stream>>>(ent, key_w, key_b, ws+o_key, 65536,128,256);
  // 2) end-embedding row + zero row 512
  fixup_end<<<128,128,0,stream>>>(en, end_emb, ws+o_key);
  // 3) gather selected rows / 512
  gather_kr<<<4096,256,0,stream>>>(su, ws+o_key, ws+o_KR);
  // 4) T1 = relu(KR @ e1_w^T + e1_b)
  gemm_kernel<false,true,false><<<dim3(128,4),256,0,stream>>>(ws+o_KR, e1_w, e1_b, ws+o_T1, 8192,256,128);
  // 5) q1e = q1_w @ e2_w   (fused 256x256 weight)
  gemm_kernel<true,false,false><<<dim3(4,4),256,0,stream>>>(q1_w, e2_w, nullptr, ws+o_q1e, 256,256,1024);
  // 6) c0 = q1_w @ e2_b
  c0_kernel<<<1,256,0,stream>>>(q1_w, e2_b, ws+o_c0);
  // 7) U0 = emb @ q1_w^T + q1_b
  gemm_kernel<false,false,false><<<dim3(2,4),256,0,stream>>>(emb, q1_w, q1_b, ws+o_U0, 128,256,1024);
  // 8) Q1K = T1 @ q1e^T
  gemm_kernel<false,false,false><<<dim3(128,4),256,0,stream>>>(ws+o_T1, ws+o_q1e, nullptr, ws+o_Q1K, 8192,256,256);
  // 9) gated exclusive prefix -> relu(U), s1, ng
  prefix_kernel<<<128,256,0,stream>>>(ws+o_U0, ws+o_Q1K, ws+o_c0, ws+o_T1, su, en, sun,
                                      ws+o_RU, ws+o_s1, ws+o_ng);
  // 10) X = RU @ q2_w^T + q2_b
  gemm_kernel<false,false,false><<<dim3(128,2),256,0,stream>>>(ws+o_RU, q2_w, q2_b, ws+o_X, 8192,128,256);
  // 11) G0 = X @ wih0^T ; then in-place LN with ln_ig0/ln_ib0
  gemm_kernel<false,false,false><<<dim3(128,8),256,0,stream>>>(ws+o_X, wih, nullptr, ws+o_G0, 8192,512,128);
  ln512<<<8192,512,0,stream>>>(ws+o_G0, ln_ig, ln_ib);
  // 12) serial LN-LSTM scan -> H1 (weights register-resident)
  lstm_serial<<<128,512,0,stream>>>(wih, whh, ws+o_G0,
                                    ln_ig, ln_ib, ln_hg, ln_hb, ln_cg, ln_cb, ws+o_H1);
  // 13) logits (masked) directly into d_out
  logits_kernel<<<128,256,0,stream>>>(ws+o_key, ws+o_H1, en, su, out);
  // 14) P = s1 @ e2_w^T ; ae = emb + P + ng*e2_b ; sun passthrough
  gemm_kernel<false,false,false><<<dim3(2,16),256,0,stream>>>(ws+o_s1, e2_w, nullptr, ws+o_P, 128,1024,256);
  ae_out_kernel<<<512,256,0,stream>>>(emb, ws+o_P, e2_b, ws+o_ng, sun, out);
}

// Round 3
// 1413.729 us; speedup vs baseline: 2.5698x; 2.5698x over previous
//
#include <hip/hip_runtime.h>
#include <hip/hip_bf16.h>
#include <math.h>

#define BSZ   128
#define NENT  512
#define NP1   513
#define DENT  256
#define KDIM  128
#define DIN   1024
#define DF    256
#define HDIM  128
#define SSTEP 64
#define G4    512
#define NEGV  (-1e9f)
#define INV_MAX (1.0f/512.0f)

// ---------------- helpers ----------------
__device__ inline float sigf(float x){ return 1.f/(1.f+__expf(-x)); }
__device__ inline float bf_lo(unsigned u){ return __uint_as_float(u<<16); }
__device__ inline float bf_hi(unsigned u){ return __uint_as_float(u & 0xffff0000u); }
__device__ inline unsigned bfpack(float lo, float hi){
  return (__float_as_uint(hi)&0xffff0000u) | (__float_as_uint(lo)>>16);
}

// block = 512 threads (8 waves). Returns sums over the block to ALL threads.
__device__ inline float2 block_reduce2(float x, float y, float* red){
  #pragma unroll
  for(int o=32;o>0;o>>=1){ x += __shfl_down(x,o,64); y += __shfl_down(y,o,64); }
  int w = threadIdx.x>>6;
  __syncthreads();
  if((threadIdx.x&63)==0){ red[w]=x; red[8+w]=y; }
  __syncthreads();
  float sx=0.f, sy=0.f;
  #pragma unroll
  for(int q=0;q<8;q++){ sx+=red[q]; sy+=red[8+q]; }
  return make_float2(sx,sy);
}

__device__ inline void block_reduce4(float a,float b,float c,float d, float* red, float out[4]){
  #pragma unroll
  for(int o=32;o>0;o>>=1){
    a += __shfl_down(a,o,64); b += __shfl_down(b,o,64);
    c += __shfl_down(c,o,64); d += __shfl_down(d,o,64);
  }
  int w = threadIdx.x>>6;
  __syncthreads();
  if((threadIdx.x&63)==0){ red[w]=a; red[8+w]=b; red[16+w]=c; red[24+w]=d; }
  __syncthreads();
  float s0=0.f,s1=0.f,s2=0.f,s3=0.f;
  #pragma unroll
  for(int q=0;q<8;q++){ s0+=red[q]; s1+=red[8+q]; s2+=red[16+q]; s3+=red[24+q]; }
  out[0]=s0; out[1]=s1; out[2]=s2; out[3]=s3;
}

// ---------------- generic tiled GEMM: C[M,N] = act(A[M,K] @ B^T + bias) ----------------
template<bool BKMAJOR, bool RELU, bool KEYMAP>
__global__ __launch_bounds__(256)
void gemm_kernel(const float* __restrict__ A, const float* __restrict__ B,
                 const float* __restrict__ bias, float* __restrict__ C,
                 int M, int N, int K){
  __shared__ float As[16][64];
  __shared__ float Bs[16][64];
  const int bm = blockIdx.x, bn = blockIdx.y;
  const int t = threadIdx.x;
  const int tm = t>>4, tn = t&15;
  float acc[16];
  #pragma unroll
  for(int q=0;q<16;q++) acc[q]=0.f;

  const int ml = t>>2;          // 0..63
  const int kq = (t&3)*4;       // 0,4,8,12

  for(int k0=0;k0<K;k0+=16){
    {
      float4 av = *(const float4*)&A[(size_t)(bm*64+ml)*K + k0 + kq];
      As[kq+0][ml]=av.x; As[kq+1][ml]=av.y; As[kq+2][ml]=av.z; As[kq+3][ml]=av.w;
    }
    if(!BKMAJOR){
      float4 bv = *(const float4*)&B[(size_t)(bn*64+ml)*K + k0 + kq];
      Bs[kq+0][ml]=bv.x; Bs[kq+1][ml]=bv.y; Bs[kq+2][ml]=bv.z; Bs[kq+3][ml]=bv.w;
    } else {
      int kl = t>>4;
      int nq = (t&15)*4;
      float4 bv = *(const float4*)&B[(size_t)(k0+kl)*N + bn*64 + nq];
      *(float4*)&Bs[kl][nq] = bv;
    }
    __syncthreads();
    #pragma unroll
    for(int k=0;k<16;k++){
      float4 a4 = *(const float4*)&As[k][tm<<2];
      float4 b4 = *(const float4*)&Bs[k][tn<<2];
      float av[4] = {a4.x,a4.y,a4.z,a4.w};
      float bv[4] = {b4.x,b4.y,b4.z,b4.w};
      #pragma unroll
      for(int mi=0;mi<4;mi++)
        #pragma unroll
        for(int ni=0;ni<4;ni++)
          acc[mi*4+ni] = fmaf(av[mi], bv[ni], acc[mi*4+ni]);
    }
    __syncthreads();
  }
  #pragma unroll
  for(int mi=0;mi<4;mi++){
    int gm = (bm<<6)+(tm<<2)+mi;
    size_t orow = KEYMAP ? ((size_t)(gm>>9)*NP1 + (gm&511)) : (size_t)gm;
    #pragma unroll
    for(int ni=0;ni<4;ni++){
      int gn = (bn<<6)+(tn<<2)+ni;
      float v = acc[mi*4+ni];
      if(bias) v += bias[gn];
      if(RELU) v = fmaxf(v,0.f);
      C[orow*N + gn] = v;
    }
  }
}

// ---------------- key fixups: end-embedding row + zero row 512 ----------------
__global__ void fixup_end(const int* __restrict__ en, const float* __restrict__ end_emb,
                          float* __restrict__ key){
  int b = blockIdx.x, k = threadIdx.x;  // 128 x 128
  int e = en[b];
  key[((size_t)b*NP1 + NENT)*KDIM + k] = 0.f;
  key[((size_t)b*NP1 + e)*KDIM + k] = end_emb[k];
}

// ---------------- gather selected key rows, scaled ----------------
__global__ void gather_kr(const int* __restrict__ su, const float* __restrict__ key,
                          float* __restrict__ KR){
  int idx = blockIdx.x*256 + threadIdx.x;  // 8192*128
  int r = idx >> 7, k = idx & 127;
  int b = r >> 6;
  int s = su[r];
  KR[idx] = key[((size_t)b*NP1 + s)*KDIM + k] * INV_MAX;
}

// ---------------- c0v[f] = q1_w[f,:] . e2_b ----------------
__global__ void c0_kernel(const float* __restrict__ q1_w, const float* __restrict__ e2_b,
                          float* __restrict__ c0v){
  int f = threadIdx.x; // 1 block x 256
  float acc=0.f;
  for(int d=0;d<DIN;d++) acc = fmaf(q1_w[(size_t)f*DIN+d], e2_b[d], acc);
  c0v[f]=acc;
}

// ---------------- gated exclusive prefix over steps; emits relu(U), s1, ng ----------------
__global__ void prefix_kernel(const float* __restrict__ U0, const float* __restrict__ Q1K,
                              const float* __restrict__ c0v, const float* __restrict__ T1,
                              const int* __restrict__ su, const int* __restrict__ en,
                              const int* __restrict__ sun,
                              float* __restrict__ RU, float* __restrict__ s1,
                              float* __restrict__ ngout){
  int b = blockIdx.x, f = threadIdx.x;    // 128 x 256
  float acc = U0[b*DF+f];
  float c0f = c0v[f];
  float s1a = 0.f, ng = 0.f;
  int enb = en[b], sunb = sun[b];
  for(int j=0;j<SSTEP;j++){
    int r = b*SSTEP+j;
    float q = Q1K[(size_t)r*DF+f];
    float tt = T1[(size_t)r*DF+f];
    RU[(size_t)r*DF+f] = fmaxf(acc,0.f);
    int sj = su[r];
    float g = ((j+1)<=sunb && sj!=enb) ? 1.f : 0.f;
    acc = fmaf(g, q + c0f, acc);
    s1a = fmaf(g, tt, s1a);
    ng += g;
  }
  s1[b*DF+f]=s1a;
  if(f==0) ngout[b]=ng;
}

// ---------------- in-place LayerNorm over rows of 512 ----------------
__global__ __launch_bounds__(512)
void ln512(float* __restrict__ G, const float* __restrict__ gam, const float* __restrict__ bet){
  __shared__ float red[32];
  size_t r = blockIdx.x;
  int j = threadIdx.x;
  float v = G[r*G4+j];
  float2 s = block_reduce2(v, v*v, red);
  float mu = s.x*(1.f/512.f);
  float rs = rsqrtf(s.y*(1.f/512.f) - mu*mu + 1e-5f);
  G[r*G4+j] = (v-mu)*rs*gam[j] + bet[j];
}

// ---------------- serial 2-layer LN-LSTM scan (1 block per batch) ----------------
// whh0 in LDS (bf16 chunk-major, conflict-free b128 reads); wih1+whh1 in 32 uint4 regs.
// LDS = 128K (W0s) + ~6K buffers -> 1 block/CU, 2 waves/SIMD; VGPR budget 256.
__global__ __launch_bounds__(512)
__attribute__((amdgpu_waves_per_eu(2,2)))
void lstm_serial(const float* __restrict__ wih, const float* __restrict__ whh,
                 const float* __restrict__ G0,
                 const float* __restrict__ ln_ig, const float* __restrict__ ln_ib,
                 const float* __restrict__ ln_hg, const float* __restrict__ ln_hb,
                 const float* __restrict__ ln_cg, const float* __restrict__ ln_cb,
                 float* __restrict__ H1){
  const int b = blockIdx.x;
  const int j = threadIdx.x;
  __shared__ uint4 W0s[16][512];       // whh0 bf16, chunk-major: [k-chunk][row]
  __shared__ float h0s[128], h1s[128], ash[512];
  __shared__ float red[32];

  // one-time: pack whh0 row j into LDS (chunk-major), wih1/whh1 row j into registers
  #pragma unroll
  for(int c=0;c<16;c++){
    float4 a = *(const float4*)&whh[(size_t)j*KDIM + c*8];
    float4 d = *(const float4*)&whh[(size_t)j*KDIM + c*8 + 4];
    uint4 p;
    p.x = bfpack(a.x,a.y); p.y = bfpack(a.z,a.w);
    p.z = bfpack(d.x,d.y); p.w = bfpack(d.z,d.w);
    W0s[c][j] = p;
  }
  uint4 w1p[16], w2p[16];
  #pragma unroll
  for(int c=0;c<16;c++){
    float4 a = *(const float4*)&wih[65536 + (size_t)j*KDIM + c*8];
    float4 d = *(const float4*)&wih[65536 + (size_t)j*KDIM + c*8 + 4];
    w1p[c].x = bfpack(a.x,a.y); w1p[c].y = bfpack(a.z,a.w);
    w1p[c].z = bfpack(d.x,d.y); w1p[c].w = bfpack(d.z,d.w);
  }
  #pragma unroll
  for(int c=0;c<16;c++){
    float4 a = *(const float4*)&whh[65536 + (size_t)j*KDIM + c*8];
    float4 d = *(const float4*)&whh[65536 + (size_t)j*KDIM + c*8 + 4];
    w2p[c].x = bfpack(a.x,a.y); w2p[c].y = bfpack(a.z,a.w);
    w2p[c].z = bfpack(d.x,d.y); w2p[c].w = bfpack(d.z,d.w);
  }

  const float hg0 = ln_hg[j],     hb0 = ln_hb[j];
  const float ig1 = ln_ig[512+j], ib1 = ln_ib[512+j];
  const float hg1 = ln_hg[512+j], hb1 = ln_hb[512+j];
  float cg0=0.f,cb0=0.f,cg1=0.f,cb1=0.f,c0r=0.f,c1r=0.f;
  if(j<128){ cg0=ln_cg[j]; cb0=ln_cb[j]; cg1=ln_cg[128+j]; cb1=ln_cb[128+j]; h0s[j]=0.f; h1s[j]=0.f; }
  __syncthreads();

  const float4* h04 = (const float4*)h0s;
  const float4* h14 = (const float4*)h1s;

  for(int i=0;i<SSTEP;i++){
    // prefetch this step's precomputed layer-0 input gates (covered by layer-0 matvec)
    float g0v = G0[((size_t)b*SSTEP+i)*G4 + j];

    // layer 0: v = whh0 @ h0  (LDS weights, LDS-broadcast h)
    float v = 0.f, vb = 0.f;
    #pragma unroll
    for(int c=0;c<16;c++){
      uint4 w = W0s[c][j];
      float4 ha = h04[2*c], hb = h04[2*c+1];
      v  = fmaf(bf_lo(w.x),ha.x,v ); v  = fmaf(bf_hi(w.x),ha.y,v );
      v  = fmaf(bf_lo(w.y),ha.z,v ); v  = fmaf(bf_hi(w.y),ha.w,v );
      vb = fmaf(bf_lo(w.z),hb.x,vb); vb = fmaf(bf_hi(w.z),hb.y,vb);
      vb = fmaf(bf_lo(w.w),hb.z,vb); vb = fmaf(bf_hi(w.w),hb.w,vb);
    }
    v += vb;
    float2 s = block_reduce2(v, v*v, red);
    float mu = s.x*(1.f/512.f);
    float rs = rsqrtf(s.y*(1.f/512.f) - mu*mu + 1e-5f);
    ash[j] = g0v + (v-mu)*rs*hg0 + hb0;
    __syncthreads();
    float cpre = 0.f;
    if(j<128){
      float gi=ash[j], gf=ash[j+128], gg=ash[j+256];
      cpre = sigf(gf)*c0r + sigf(gi)*tanhf(gg);
    }
    float2 sc = block_reduce2(j<128?cpre:0.f, j<128?cpre*cpre:0.f, red);
    float muc = sc.x*(1.f/128.f);
    float rsc = rsqrtf(sc.y*(1.f/128.f) - muc*muc + 1e-5f);
    if(j<128){
      c0r = (cpre-muc)*rsc*cg0 + cb0;
      h0s[j] = sigf(ash[j+384])*tanhf(c0r);
    }
    __syncthreads();

    // layer 1: u = wih1 @ h0,  v1 = whh1 @ h1  (register weights)
    float u=0.f, ub=0.f, v1=0.f, v1b=0.f;
    #pragma unroll
    for(int c=0;c<16;c++){
      uint4 wa = w1p[c];
      uint4 wb = w2p[c];
      float4 ha = h04[2*c], hc = h04[2*c+1];
      float4 ga = h14[2*c], gc = h14[2*c+1];
      u   = fmaf(bf_lo(wa.x),ha.x,u  ); u   = fmaf(bf_hi(wa.x),ha.y,u  );
      u   = fmaf(bf_lo(wa.y),ha.z,u  ); u   = fmaf(bf_hi(wa.y),ha.w,u  );
      ub  = fmaf(bf_lo(wa.z),hc.x,ub ); ub  = fmaf(bf_hi(wa.z),hc.y,ub );
      ub  = fmaf(bf_lo(wa.w),hc.z,ub ); ub  = fmaf(bf_hi(wa.w),hc.w,ub );
      v1  = fmaf(bf_lo(wb.x),ga.x,v1 ); v1  = fmaf(bf_hi(wb.x),ga.y,v1 );
      v1  = fmaf(bf_lo(wb.y),ga.z,v1 ); v1  = fmaf(bf_hi(wb.y),ga.w,v1 );
      v1b = fmaf(bf_lo(wb.z),gc.x,v1b); v1b = fmaf(bf_hi(wb.z),gc.y,v1b);
      v1b = fmaf(bf_lo(wb.w),gc.z,v1b); v1b = fmaf(bf_hi(wb.w),gc.w,v1b);
    }
    u += ub; v1 += v1b;
    float s4[4];
    block_reduce4(u,u*u,v1,v1*v1,red,s4);
    float muu = s4[0]*(1.f/512.f);
    float rsu = rsqrtf(s4[1]*(1.f/512.f) - muu*muu + 1e-5f);
    float muv = s4[2]*(1.f/512.f);
    float rsv = rsqrtf(s4[3]*(1.f/512.f) - muv*muv + 1e-5f);
    ash[j] = (u-muu)*rsu*ig1 + ib1 + (v1-muv)*rsv*hg1 + hb1;
    __syncthreads();
    float cpre1 = 0.f;
    if(j<128){
      float gi=ash[j], gf=ash[j+128], gg=ash[j+256];
      cpre1 = sigf(gf)*c1r + sigf(gi)*tanhf(gg);
    }
    float2 sc1 = block_reduce2(j<128?cpre1:0.f, j<128?cpre1*cpre1:0.f, red);
    float muc1 = sc1.x*(1.f/128.f);
    float rsc1 = rsqrtf(sc1.y*(1.f/128.f) - muc1*muc1 + 1e-5f);
    if(j<128){
      c1r = (cpre1-muc1)*rsc1*cg1 + cb1;
      float h1n = sigf(ash[j+384])*tanhf(c1r);
      h1s[j] = h1n;
      H1[((size_t)b*SSTEP+i)*HDIM + j] = h1n;
    }
    __syncthreads();
  }
}

// ---------------- logits: per-batch H1 @ key^T with mask ----------------
__global__ __launch_bounds__(256)
void logits_kernel(const float* __restrict__ key, const float* __restrict__ H1,
                   const int* __restrict__ en, const int* __restrict__ su,
                   float* __restrict__ out){
  const int b = blockIdx.x;
  __shared__ float HsT[128][68];       // [k][i], padded
  __shared__ int firstsel[NP1];
  for(int t=threadIdx.x; t<SSTEP*HDIM; t+=256){
    int i = t>>7, k = t&127;
    HsT[k][i] = H1[(size_t)b*SSTEP*HDIM + t];
  }
  for(int t=threadIdx.x; t<NP1; t+=256) firstsel[t] = 1<<30;
  __syncthreads();
  if(threadIdx.x < SSTEP) atomicMin(&firstsel[su[b*SSTEP+threadIdx.x]], (int)threadIdx.x);
  __syncthreads();
  const int enb = en[b];
  for(int n=threadIdx.x; n<NP1; n+=256){
    if(n > enb){
      for(int i=0;i<SSTEP;i++) out[((size_t)b*SSTEP+i)*NP1 + n] = NEGV;
      continue;
    }
    const float* kr = key + ((size_t)b*NP1 + n)*KDIM;
    const int fs = firstsel[n];
    for(int it=0; it<SSTEP; it+=16){
      float acc[16];
      #pragma unroll
      for(int q=0;q<16;q++) acc[q]=0.f;
      for(int k=0;k<KDIM;k+=4){
        float4 kv = *(const float4*)&kr[k];
        float kvs[4] = {kv.x,kv.y,kv.z,kv.w};
        #pragma unroll
        for(int kk=0;kk<4;kk++){
          #pragma unroll
          for(int qq=0;qq<4;qq++){
            float4 hv = *(const float4*)&HsT[k+kk][it+qq*4];
            acc[qq*4+0] = fmaf(kvs[kk], hv.x, acc[qq*4+0]);
            acc[qq*4+1] = fmaf(kvs[kk], hv.y, acc[qq*4+1]);
            acc[qq*4+2] = fmaf(kvs[kk], hv.z, acc[qq*4+2]);
            acc[qq*4+3] = fmaf(kvs[kk], hv.w, acc[qq*4+3]);
          }
        }
      }
      #pragma unroll
      for(int q=0;q<16;q++){
        int i = it+q;
        bool m = (fs >= i) && !(i==0 && n==enb);
        out[((size_t)b*SSTEP+i)*NP1 + n] = m ? acc[q] : NEGV;
      }
    }
  }
}

// ---------------- final ae + selected_units_num ----------------
__global__ void ae_out_kernel(const float* __restrict__ emb, const float* __restrict__ P,
                              const float* __restrict__ e2_b, const float* __restrict__ ng,
                              const int* __restrict__ sun, float* __restrict__ out){
  const size_t AE_OFF = (size_t)BSZ*SSTEP*NP1;
  const size_t SUN_OFF = AE_OFF + (size_t)BSZ*DIN;
  int idx = blockIdx.x*256+threadIdx.x;   // 131072
  int b = idx>>10, d = idx&1023;
  out[AE_OFF + idx] = emb[idx] + P[idx] + ng[b]*e2_b[d];
  if(idx < BSZ) out[SUN_OFF + idx] = (float)sun[idx];
}

// ---------------- launch ----------------
extern "C" void kernel_launch(void* const* d_in, const int* in_sizes, int n_in,
                              void* d_out, int out_size, void* d_ws, size_t ws_size,
                              hipStream_t stream){
  const float* emb     = (const float*)d_in[0];
  const float* ent     = (const float*)d_in[1];
  const float* key_w   = (const float*)d_in[2];
  const float* key_b   = (const float*)d_in[3];
  const float* q1_w    = (const float*)d_in[4];
  const float* q1_b    = (const float*)d_in[5];
  const float* q2_w    = (const float*)d_in[6];
  const float* q2_b    = (const float*)d_in[7];
  const float* e1_w    = (const float*)d_in[8];
  const float* e1_b    = (const float*)d_in[9];
  const float* e2_w    = (const float*)d_in[10];
  const float* e2_b    = (const float*)d_in[11];
  const float* end_emb = (const float*)d_in[12];
  const float* wih     = (const float*)d_in[13];
  const float* whh     = (const float*)d_in[14];
  const float* ln_ig   = (const float*)d_in[15];
  const float* ln_ib   = (const float*)d_in[16];
  const float* ln_hg   = (const float*)d_in[17];
  const float* ln_hb   = (const float*)d_in[18];
  const float* ln_cg   = (const float*)d_in[19];
  const float* ln_cb   = (const float*)d_in[20];
  const int* en  = (const int*)d_in[21];
  const int* su  = (const int*)d_in[22];
  const int* sun = (const int*)d_in[23];
  float* out = (float*)d_out;
  float* ws  = (float*)d_ws;

  // workspace layout (float units)
  const size_t o_key = 0;                       // 128*513*128 = 8,404,992
  const size_t o_KR  = o_key + 8404992;         // 1,048,576
  const size_t o_T1  = o_KR  + 1048576;         // 2,097,152
  const size_t o_q1e = o_T1  + 2097152;         // 65,536
  const size_t o_c0  = o_q1e + 65536;           // 1,024 (256 used)
  const size_t o_U0  = o_c0  + 1024;            // 32,768
  const size_t o_Q1K = o_U0  + 32768;           // 2,097,152
  const size_t o_RU  = o_Q1K + 2097152;         // 2,097,152
  const size_t o_X   = o_RU  + 2097152;         // 1,048,576
  const size_t o_G0  = o_X   + 1048576;         // 4,194,304
  const size_t o_s1  = o_G0  + 4194304;         // 32,768
  const size_t o_ng  = o_s1  + 32768;           // 1,024 (128 used)
  const size_t o_H1  = o_ng  + 1024;            // 1,048,576
  const size_t o_P   = o_H1  + 1048576;         // 131,072

  // 1) key = ent_emb @ key_w^T + key_b  (rows mapped into 513-stride layout)
  gemm_kernel<false,false,true><<<dim3(1024,2),256,0,stream>>>(ent, key_w, key_b, ws+o_key, 65536,128,256);
  // 2) end-embedding row + zero row 512
  fixup_end<<<128,128,0,stream>>>(en, end_emb, ws+o_key);
  // 3) gather selected rows / 512
  gather_kr<<<4096,256,0,stream>>>(su, ws+o_key, ws+o_KR);
  // 4) T1 = relu(KR @ e1_w^T + e1_b)
  gemm_kernel<false,true,false><<<dim3(128,4),256,0,stream>>>(ws+o_KR, e1_w, e1_b, ws+o_T1, 8192,256,128);
  // 5) q1e = q1_w @ e2_w   (fused 256x256 weight)
  gemm_kernel<true,false,false><<<dim3(4,4),256,0,stream>>>(q1_w, e2_w, nullptr, ws+o_q1e, 256,256,1024);
  // 6) c0 = q1_w @ e2_b
  c0_kernel<<<1,256,0,stream>>>(q1_w, e2_b, ws+o_c0);
  // 7) U0 = emb @ q1_w^T + q1_b
  gemm_kernel<false,false,false><<<dim3(2,4),256,0,stream>>>(emb, q1_w, q1_b, ws+o_U0, 128,256,1024);
  // 8) Q1K = T1 @ q1e^T
  gemm_kernel<false,false,false><<<dim3(128,4),256,0,stream>>>(ws+o_T1, ws+o_q1e, nullptr, ws+o_Q1K, 8192,256,256);
  // 9) gated exclusive prefix -> relu(U), s1, ng
  prefix_kernel<<<128,256,0,stream>>>(ws+o_U0, ws+o_Q1K, ws+o_c0, ws+o_T1, su, en, sun,
                                      ws+o_RU, ws+o_s1, ws+o_ng);
  // 10) X = RU @ q2_w^T + q2_b
  gemm_kernel<false,false,false><<<dim3(128,2),256,0,stream>>>(ws+o_RU, q2_w, q2_b, ws+o_X, 8192,128,256);
  // 11) G0 = X @ wih0^T ; then in-place LN with ln_ig0/ln_ib0
  gemm_kernel<false,false,false><<<dim3(128,8),256,0,stream>>>(ws+o_X, wih, nullptr, ws+o_G0, 8192,512,128);
  ln512<<<8192,512,0,stream>>>(ws+o_G0, ln_ig, ln_ib);
  // 12) serial LN-LSTM scan -> H1 (whh0 in LDS, wih1/whh1 register-resident)
  lstm_serial<<<128,512,0,stream>>>(wih, whh, ws+o_G0,
                                    ln_ig, ln_ib, ln_hg, ln_hb, ln_cg, ln_cb, ws+o_H1);
  // 13) logits (masked) directly into d_out
  logits_kernel<<<128,256,0,stream>>>(ws+o_key, ws+o_H1, en, su, out);
  // 14) P = s1 @ e2_w^T ; ae = emb + P + ng*e2_b ; sun passthrough
  gemm_kernel<false,false,false><<<dim3(2,16),256,0,stream>>>(ws+o_s1, e2_w, nullptr, ws+o_P, 128,1024,256);
  ae_out_kernel<<<512,256,0,stream>>>(emb, ws+o_P, e2_b, ws+o_ng, sun, out);
}